// Round 11
// baseline (117.945 us; speedup 1.0000x reference)
//
#include <hip/hip_runtime.h>
#include <math.h>

#define PP 4
#define BB 32
#define PB (PP * BB)
#define NN 2048
#define MM 512
#define DLAT 128
#define BETA_C 1e-3f
#define BIGV 1e9f
#define SENT 1e8f
#define THREADS 512
#define NWAVE 8
#define XCHUNKS 4
#define QCH (NN / XCHUNKS)    // 512 n-range per x-chunk
#define XMAX (QCH + 32)

// g_ws layout (floats), every cell written by exactly one block per launch:
//   [0,512)            qual[z][pb]
//   [512,1024)         nx[z][pb]
//   [1024,1152)        cov[pb]        (written by colsum)
//   [1152,1280)        ny[pb]         (written by colsum)
//   [2048, 2048+4*PB*512) colmin[z][pb][j]
#define GW_QUAL(z, pb)   ((z) * PB + (pb))
#define GW_NX(z, pb)     (512 + (z) * PB + (pb))
#define GW_COV(pb)       (1024 + (pb))
#define GW_NY(pb)        (1152 + (pb))
#define GW_COL(z, pb, j) (2048 + (((z) * PB + (pb)) * 512) + (j))
__device__ float g_ws[2048 + 4 * PB * 512];

__device__ __forceinline__ int wave_compact_slot(bool sel, int* s_cnt, int lane) {
    unsigned long long bal = __ballot(sel);
    int lofs = __popcll(bal & ((1ull << lane) - 1ull));
    int base = 0;
    if (lane == 0 && bal) base = atomicAdd(s_cnt, __popcll(bal));
    base = __shfl(base, 0);
    return base + lofs;
}

// One block per (b, i, z): x-chunk z. Computes D once: row-min (quality, as
// round-10) AND col-min partials (coverage) via per-j wave butterfly, written
// to disjoint g_ws colmin planes. Coverage's 4x redundant full-N scans are gone.
__global__ __launch_bounds__(THREADS, 8) void parts_kernel(
    const float* __restrict__ ipt,    // (B,N,3)
    const float* __restrict__ opt,    // (P,B,M,3)
    const float* __restrict__ trans,  // (P,B,3)
    const float* __restrict__ rots,   // (P,B,4)
    const int*   __restrict__ idx)    // (B,N)
{
    const int b = blockIdx.x;
    const int i = blockIdx.y;
    const int z = blockIdx.z;
    const int tid = threadIdx.x;
    const int lane = tid & 63;
    const int w = tid >> 6;

    __shared__ float Rm[12];
    __shared__ int s_nx;
    __shared__ __align__(16) float syx[MM], syy[MM], syz[MM];   // SENT-sanitized y
    __shared__ __align__(16) float sxx[XMAX], sxy[XMAX], sxz[XMAX];
    __shared__ float pmin[NWAVE][128];
    __shared__ float colw[NWAVE][64];   // per-wave col-min over this chunk's x
    __shared__ float red[NWAVE];

    if (tid == 0) {
        s_nx = 0;
        const float* q = rots + (i * BB + b) * 4;
        float qw = q[0], qx = q[1], qy = q[2], qz = q[3];
        float inv = 1.0f / sqrtf(qw * qw + qx * qx + qy * qy + qz * qz);
        qw *= inv; qx *= inv; qy *= inv; qz *= inv;
        Rm[0] = 1.0f - 2.0f * (qy * qy + qz * qz);
        Rm[1] = 2.0f * (qx * qy - qw * qz);
        Rm[2] = 2.0f * (qx * qz + qw * qy);
        Rm[3] = 2.0f * (qx * qy + qw * qz);
        Rm[4] = 1.0f - 2.0f * (qx * qx + qz * qz);
        Rm[5] = 2.0f * (qy * qz - qw * qx);
        Rm[6] = 2.0f * (qx * qz - qw * qy);
        Rm[7] = 2.0f * (qy * qz + qw * qx);
        Rm[8] = 1.0f - 2.0f * (qx * qx + qy * qy);
        const float* t = trans + (i * BB + b) * 3;
        Rm[9] = t[0]; Rm[10] = t[1]; Rm[11] = t[2];
    }
    colw[w][lane] = BIGV;               // wave-local, no sync needed
    __syncthreads();

    const float R0 = Rm[0], R1 = Rm[1], R2 = Rm[2];
    const float R3 = Rm[3], R4 = Rm[4], R5 = Rm[5];
    const float R6 = Rm[6], R7 = Rm[7], R8 = Rm[8];
    const float t0 = Rm[9], t1 = Rm[10], t2 = Rm[11];
    const size_t optbase = ((size_t)i * BB + b) * MM;
    const int pb = i * BB + b;

    // stage all 512 y (1 iter @ 512 thr); invalid -> SENT (colsum re-gates validity)
    {
        const float* y = opt + (optbase + tid) * 3;
        float yx = y[0], yy = y[1], yz = y[2];
        bool v = (yx != 0.0f) | (yy != 0.0f) | (yz != 0.0f);
        if (!v) { yx = SENT; yy = SENT; yz = SENT; }
        syx[tid] = yx; syy[tid] = yy; syz[tid] = yz;
    }
    // compact + transform x from this chunk's n-range (1 iter @ 512 thr)
    {
        const int n = z * QCH + tid;
        const float* p = ipt + ((size_t)b * NN + n) * 3;
        float px = p[0], py = p[1], pz = p[2];
        bool nz = (px != 0.0f) | (py != 0.0f) | (pz != 0.0f);
        bool sel = nz && (idx[b * NN + n] == i);
        int pos = wave_compact_slot(sel, &s_nx, lane);
        if (sel) {
            px -= t0; py -= t1; pz -= t2;
            sxx[pos] = R0 * px + R1 * py + R2 * pz;
            sxy[pos] = R3 * px + R4 * py + R5 * pz;
            sxz[pos] = R6 * px + R7 * py + R8 * pz;
        }
    }
    __syncthreads();
    const int nxc = s_nx;
    const int y0 = w * 64;              // this wave's 64-y slice

    float sum = 0.0f;
    for (int base = 0; base < nxc; base += 128) {   // typically one pass (nxc~128)
        float px[2], py[2], pz[2], mn[2];
#pragma unroll
        for (int s = 0; s < 2; ++s) {
            int k = base + s * 64 + lane;
            bool a = (k < nxc);
            px[s] = a ? sxx[k] : SENT;              // inactive -> huge d (col +inf)
            py[s] = a ? sxy[k] : SENT;
            pz[s] = a ? sxz[k] : SENT;
            mn[s] = BIGV;
        }
        for (int it = 0; it < 16; ++it) {           // 4 y per iter
            const int j = it * 4;
            float4 yx = *reinterpret_cast<const float4*>(syx + y0 + j);
            float4 yy = *reinterpret_cast<const float4*>(syy + y0 + j);
            float4 yz = *reinterpret_cast<const float4*>(syz + y0 + j);
            float c0 = BIGV, c1 = BIGV, c2 = BIGV, c3 = BIGV;
#pragma unroll
            for (int s = 0; s < 2; ++s) {
                float dx0 = px[s] - yx.x, dy0 = py[s] - yy.x, dz0 = pz[s] - yz.x;
                float dx1 = px[s] - yx.y, dy1 = py[s] - yy.y, dz1 = pz[s] - yz.y;
                float dx2 = px[s] - yx.z, dy2 = py[s] - yy.z, dz2 = pz[s] - yz.z;
                float dx3 = px[s] - yx.w, dy3 = py[s] - yy.w, dz3 = pz[s] - yz.w;
                float d0 = dx0 * dx0 + dy0 * dy0 + dz0 * dz0;
                float d1 = dx1 * dx1 + dy1 * dy1 + dz1 * dz1;
                float d2 = dx2 * dx2 + dy2 * dy2 + dz2 * dz2;
                float d3 = dx3 * dx3 + dy3 * dy3 + dz3 * dz3;
                mn[s] = fminf(mn[s], fminf(fminf(d0, d1), fminf(d2, d3)));  // row-min
                c0 = fminf(c0, d0); c1 = fminf(c1, d1);                      // col partial
                c2 = fminf(c2, d2); c3 = fminf(c3, d3);
            }
            // wave-min butterfly for the 4 col values (64 lanes -> all hold min)
#pragma unroll
            for (int m = 1; m < 64; m <<= 1) {
                c0 = fminf(c0, __shfl_xor(c0, m));
                c1 = fminf(c1, __shfl_xor(c1, m));
                c2 = fminf(c2, __shfl_xor(c2, m));
                c3 = fminf(c3, __shfl_xor(c3, m));
            }
            // owner lanes j..j+3 accumulate (static cndmask select, no dyn index)
            if ((lane >> 2) == it) {
                int r = lane & 3;
                float v = (r == 0) ? c0 : (r == 1) ? c1 : (r == 2) ? c2 : c3;
                colw[w][lane] = fminf(colw[w][lane], v);
            }
        }
#pragma unroll
        for (int s = 0; s < 2; ++s) pmin[w][s * 64 + lane] = mn[s];
        __syncthreads();
        if (tid < 128 && base + tid < nxc) {        // row-min combine across waves
            float m = pmin[0][tid];
#pragma unroll
            for (int ww = 1; ww < NWAVE; ++ww) m = fminf(m, pmin[ww][tid]);
            sum += m;
        }
        __syncthreads();
    }

    // write col-min partial plane (disjoint per block; BIGV if nxc==0)
    g_ws[GW_COL(z, pb, y0 + lane)] = colw[w][lane];

    for (int off = 32; off > 0; off >>= 1) sum += __shfl_down(sum, off);
    if (lane == 0) red[w] = sum;
    __syncthreads();
    if (tid == 0) {
        float tot = 0.0f;
        for (int ww = 0; ww < NWAVE; ++ww) tot += red[ww];
        g_ws[GW_QUAL(z, pb)] = tot;
        g_ws[GW_NX(z, pb)] = (float)nxc;
    }
}

// One block per pb=(i,b): min-combine the 4 colmin planes, gate by y-validity,
// produce cov sum + ny.
__global__ __launch_bounds__(256) void colsum_kernel(
    const float* __restrict__ opt)
{
    const int pb = blockIdx.x;
    const int tid = threadIdx.x;
    __shared__ float red[4];
    __shared__ int redc[4];

    const size_t optbase = (size_t)pb * MM;
    float sum = 0.0f;
    int cnt = 0;
#pragma unroll
    for (int s = 0; s < 2; ++s) {
        int j = s * 256 + tid;
        const float* y = opt + (optbase + j) * 3;
        bool v = (y[0] != 0.0f) | (y[1] != 0.0f) | (y[2] != 0.0f);
        float m = fminf(fminf(g_ws[GW_COL(0, pb, j)], g_ws[GW_COL(1, pb, j)]),
                        fminf(g_ws[GW_COL(2, pb, j)], g_ws[GW_COL(3, pb, j)]));
        if (v) { sum += m; cnt++; }     // nx==0 -> m=BIGV, gated in finalize
    }
    for (int off = 32; off > 0; off >>= 1) {
        sum += __shfl_down(sum, off);
        cnt += __shfl_down(cnt, off);
    }
    if ((tid & 63) == 0) { red[tid >> 6] = sum; redc[tid >> 6] = cnt; }
    __syncthreads();
    if (tid == 0) {
        g_ws[GW_COV(pb)] = red[0] + red[1] + red[2] + red[3];
        g_ws[GW_NY(pb)] = (float)(redc[0] + redc[1] + redc[2] + redc[3]);
    }
}

__global__ __launch_bounds__(256) void finalize_kernel(
    const float* __restrict__ probs,   // (P,B,1)
    const float* __restrict__ mu,      // (B,DLAT)
    const float* __restrict__ logvar,  // (B,DLAT)
    float* __restrict__ out)
{
    const int tid = threadIdx.x;
    __shared__ float red[4];
    __shared__ float s_wq[PB], s_wc[PB], s_val[PB];

    const float4* mu4 = reinterpret_cast<const float4*>(mu);
    const float4* lv4 = reinterpret_cast<const float4*>(logvar);
    float kls = 0.0f;
    for (int t = tid; t < BB * DLAT / 4; t += 256) {
        float4 m4 = mu4[t], l4 = lv4[t];
        kls += (1.0f + l4.x - m4.x * m4.x - expf(l4.x))
             + (1.0f + l4.y - m4.y * m4.y - expf(l4.y))
             + (1.0f + l4.z - m4.z * m4.z - expf(l4.z))
             + (1.0f + l4.w - m4.w * m4.w - expf(l4.w));
    }
    for (int off = 32; off > 0; off >>= 1) kls += __shfl_down(kls, off);
    if ((tid & 63) == 0) red[tid >> 6] = kls;

    if (tid < PB) {
        float qs  = g_ws[GW_QUAL(0, tid)] + g_ws[GW_QUAL(1, tid)]
                  + g_ws[GW_QUAL(2, tid)] + g_ws[GW_QUAL(3, tid)];
        float nxf = g_ws[GW_NX(0, tid)] + g_ws[GW_NX(1, tid)]
                  + g_ws[GW_NX(2, tid)] + g_ws[GW_NX(3, tid)];
        float cs  = g_ws[GW_COV(tid)];
        float nyf = g_ws[GW_NY(tid)];
        bool valid = (nxf > 0.0f) && (nyf > 0.0f);
        float wgt = valid ? probs[tid] : 0.0f;
        s_wq[tid] = wgt * (qs / fmaxf(nxf, 1.0f));
        s_wc[tid] = wgt * (cs / fmaxf(nyf, 1.0f));
        s_val[tid] = valid ? 1.0f : 0.0f;
    }
    __syncthreads();

    if (tid == 0) {
        float kld = -0.5f * (red[0] + red[1] + red[2] + red[3]) / (float)BB;
        float ch = 0.0f, cov = 0.0f, qu = 0.0f, num = 0.0f;
        for (int ii = 0; ii < PP; ++ii) {
            float sq = 0.0f, sc = 0.0f, n = 0.0f;
            for (int bb = 0; bb < BB; ++bb) {
                sq += s_wq[ii * BB + bb];
                sc += s_wc[ii * BB + bb];
                n += s_val[ii * BB + bb];
            }
            float has = (n > 0.0f) ? 1.0f : 0.0f;
            float invn = has / fmaxf(n, 1.0f);
            qu += sq * invn;
            cov += sc * invn;
            ch += (sq + sc) * invn;
            num += has;
        }
        float invnum = 1.0f / fmaxf(num, 1.0f);
        float cds = ch * invnum;
        out[0] = cds + BETA_C * kld;
        out[1] = cds;
        out[2] = cov * invnum;
        out[3] = qu * invnum;
        out[4] = kld;
    }
}

extern "C" void kernel_launch(void* const* d_in, const int* in_sizes, int n_in,
                              void* d_out, int out_size, void* d_ws, size_t ws_size,
                              hipStream_t stream) {
    const float* ipt    = (const float*)d_in[0];
    const float* opt    = (const float*)d_in[1];
    const float* trans  = (const float*)d_in[2];
    const float* rots   = (const float*)d_in[3];
    const float* probs  = (const float*)d_in[4];
    const int*   idx    = (const int*)d_in[5];
    const float* mu     = (const float*)d_in[6];
    const float* logvar = (const float*)d_in[7];
    float* out = (float*)d_out;
    (void)d_ws; (void)ws_size; (void)in_sizes; (void)n_in; (void)out_size;

    dim3 grid(BB, PP, XCHUNKS);
    parts_kernel<<<grid, THREADS, 0, stream>>>(ipt, opt, trans, rots, idx);
    colsum_kernel<<<PB, 256, 0, stream>>>(opt);
    finalize_kernel<<<1, 256, 0, stream>>>(probs, mu, logvar, out);
}

// Round 12
// 94.285 us; speedup vs baseline: 1.2509x; 1.2509x over previous
//
#include <hip/hip_runtime.h>
#include <math.h>

#define PP 4
#define BB 32
#define PB (PP * BB)
#define NN 2048
#define MM 512
#define DLAT 128
#define BETA_C 1e-3f
#define BIGV 1e9f
#define SENT 1e8f
#define THREADS 512
#define NWAVE 8
#define XCHUNKS 8
#define QCH (NN / XCHUNKS)    // 256 n-range per x-chunk
#define XMAX (QCH + 8)

// g_ws layout (floats), every cell written by exactly one block per launch:
//   [0,1024)   qual[z][pb]   (z<8)
//   [1024,2048) nx[z][pb]
//   [2048,2176) cov[pb]      (colsum)
//   [2176,2304) ny[pb]       (colsum)
//   [4096, ...) colmin[z][pb][j]  j<512
#define GW_QUAL(z, pb)   ((z) * PB + (pb))
#define GW_NX(z, pb)     (1024 + (z) * PB + (pb))
#define GW_COV(pb)       (2048 + (pb))
#define GW_NY(pb)        (2176 + (pb))
#define GW_COL(z, pb, j) (4096 + (((z) * PB + (pb)) * 512) + (j))
__device__ float g_ws[4096 + XCHUNKS * PB * 512];

__device__ __forceinline__ int wave_compact_slot(bool sel, int* s_cnt, int lane) {
    unsigned long long bal = __ballot(sel);
    int lofs = __popcll(bal & ((1ull << lane) - 1ull));
    int base = 0;
    if (lane == 0 && bal) base = atomicAdd(s_cnt, __popcll(bal));
    base = __shfl(base, 0);
    return base + lofs;
}

// One block per (b, i, z): x-chunk z. Stage y + compact x ONCE, then:
// pass 1 row-min (quality): lane holds an x, streams y  -> min is lane-local.
// pass 2 col-min (coverage): lane holds a y, streams x  -> min is lane-local.
// (round-11 lesson: NO per-element cross-lane reduction.)
__global__ __launch_bounds__(THREADS, 8) void parts_kernel(
    const float* __restrict__ ipt,    // (B,N,3)
    const float* __restrict__ opt,    // (P,B,M,3)
    const float* __restrict__ trans,  // (P,B,3)
    const float* __restrict__ rots,   // (P,B,4)
    const int*   __restrict__ idx)    // (B,N)
{
    const int b = blockIdx.x;
    const int i = blockIdx.y;
    const int z = blockIdx.z;
    const int tid = threadIdx.x;
    const int lane = tid & 63;
    const int w = tid >> 6;

    __shared__ float Rm[12];
    __shared__ int s_nx;
    __shared__ __align__(16) float syx[MM], syy[MM], syz[MM];   // SENT-sanitized y
    __shared__ __align__(16) float sxx[XMAX], sxy[XMAX], sxz[XMAX];
    __shared__ float pmin[NWAVE][64];

    if (tid == 0) {
        s_nx = 0;
        const float* q = rots + (i * BB + b) * 4;
        float qw = q[0], qx = q[1], qy = q[2], qz = q[3];
        float inv = 1.0f / sqrtf(qw * qw + qx * qx + qy * qy + qz * qz);
        qw *= inv; qx *= inv; qy *= inv; qz *= inv;
        Rm[0] = 1.0f - 2.0f * (qy * qy + qz * qz);
        Rm[1] = 2.0f * (qx * qy - qw * qz);
        Rm[2] = 2.0f * (qx * qz + qw * qy);
        Rm[3] = 2.0f * (qx * qy + qw * qz);
        Rm[4] = 1.0f - 2.0f * (qx * qx + qz * qz);
        Rm[5] = 2.0f * (qy * qz - qw * qx);
        Rm[6] = 2.0f * (qx * qz - qw * qy);
        Rm[7] = 2.0f * (qy * qz + qw * qx);
        Rm[8] = 1.0f - 2.0f * (qx * qx + qy * qy);
        const float* t = trans + (i * BB + b) * 3;
        Rm[9] = t[0]; Rm[10] = t[1]; Rm[11] = t[2];
    }
    __syncthreads();

    const float R0 = Rm[0], R1 = Rm[1], R2 = Rm[2];
    const float R3 = Rm[3], R4 = Rm[4], R5 = Rm[5];
    const float R6 = Rm[6], R7 = Rm[7], R8 = Rm[8];
    const float t0 = Rm[9], t1 = Rm[10], t2 = Rm[11];
    const size_t optbase = ((size_t)i * BB + b) * MM;
    const int pb = i * BB + b;

    // stage all 512 y (1 iter @ 512 thr); invalid -> SENT (colsum re-gates validity)
    {
        const float* y = opt + (optbase + tid) * 3;
        float yx = y[0], yy = y[1], yz = y[2];
        bool v = (yx != 0.0f) | (yy != 0.0f) | (yz != 0.0f);
        if (!v) { yx = SENT; yy = SENT; yz = SENT; }
        syx[tid] = yx; syy[tid] = yy; syz[tid] = yz;
    }
    // compact + transform x from this chunk's 256-n-range (threads >= QCH idle)
    {
        bool inr = tid < QCH;
        int n = z * QCH + (inr ? tid : 0);
        const float* p = ipt + ((size_t)b * NN + n) * 3;
        float px = p[0], py = p[1], pz = p[2];
        bool nz = (px != 0.0f) | (py != 0.0f) | (pz != 0.0f);
        bool sel = inr && nz && (idx[b * NN + n] == i);
        int pos = wave_compact_slot(sel, &s_nx, lane);
        if (sel) {
            px -= t0; py -= t1; pz -= t2;
            sxx[pos] = R0 * px + R1 * py + R2 * pz;
            sxy[pos] = R3 * px + R4 * py + R5 * pz;
            sxz[pos] = R6 * px + R7 * py + R8 * pz;
        }
    }
    __syncthreads();
    const int nxc = s_nx;
    const int nx4 = (nxc + 3) & ~3;
    if (tid < nx4 - nxc) {              // pad so pass-2 b128 streaming is aligned
        sxx[nxc + tid] = SENT; sxy[nxc + tid] = SENT; sxz[nxc + tid] = SENT;
    }
    __syncthreads();

    // ---- pass 1: row-min (quality). 1 x-slot/lane, stream wave's 64-y slice ----
    const int y0 = w * 64;
    float sum = 0.0f;
    for (int base = 0; base < nxc; base += 64) {    // ~1 pass (nxc ~ 64)
        int k = base + lane;
        bool a = (k < nxc);
        float px = a ? sxx[k] : SENT;
        float py = a ? sxy[k] : SENT;
        float pz = a ? sxz[k] : SENT;
        float mna = BIGV, mnb = BIGV;
        for (int it = 0; it < 16; ++it) {           // wave-uniform broadcast b128
            const int j = y0 + it * 4;
            float4 yx = *reinterpret_cast<const float4*>(syx + j);
            float4 yy = *reinterpret_cast<const float4*>(syy + j);
            float4 yz = *reinterpret_cast<const float4*>(syz + j);
            float dx0 = px - yx.x, dy0 = py - yy.x, dz0 = pz - yz.x;
            float dx1 = px - yx.y, dy1 = py - yy.y, dz1 = pz - yz.y;
            float dx2 = px - yx.z, dy2 = py - yy.z, dz2 = pz - yz.z;
            float dx3 = px - yx.w, dy3 = py - yy.w, dz3 = pz - yz.w;
            float d0 = dx0 * dx0 + dy0 * dy0 + dz0 * dz0;
            float d1 = dx1 * dx1 + dy1 * dy1 + dz1 * dz1;
            float d2 = dx2 * dx2 + dy2 * dy2 + dz2 * dz2;
            float d3 = dx3 * dx3 + dy3 * dy3 + dz3 * dz3;
            mna = fminf(mna, fminf(d0, d1));        // dual chains break dep latency
            mnb = fminf(mnb, fminf(d2, d3));
        }
        pmin[w][lane] = fminf(mna, mnb);
        __syncthreads();
        if (tid < 64 && base + tid < nxc) {         // combine 8 wave y-slices
            float m = pmin[0][tid];
#pragma unroll
            for (int ww = 1; ww < NWAVE; ++ww) m = fminf(m, pmin[ww][tid]);
            sum += m;                               // sum lives on wave 0 only
        }
        __syncthreads();
    }

    // ---- pass 2: col-min (coverage). lane owns y `tid`, streams chunk's x ----
    {
        float cqx = syx[tid], cqy = syy[tid], cqz = syz[tid];
        float ca = BIGV, cb = BIGV;
        for (int k = 0; k < nx4; k += 4) {          // wave-uniform broadcast b128
            float4 xx = *reinterpret_cast<const float4*>(sxx + k);
            float4 xy = *reinterpret_cast<const float4*>(sxy + k);
            float4 xz = *reinterpret_cast<const float4*>(sxz + k);
            float dx0 = cqx - xx.x, dy0 = cqy - xy.x, dz0 = cqz - xz.x;
            float dx1 = cqx - xx.y, dy1 = cqy - xy.y, dz1 = cqz - xz.y;
            float dx2 = cqx - xx.z, dy2 = cqy - xy.z, dz2 = cqz - xz.z;
            float dx3 = cqx - xx.w, dy3 = cqy - xy.w, dz3 = cqz - xz.w;
            float d0 = dx0 * dx0 + dy0 * dy0 + dz0 * dz0;
            float d1 = dx1 * dx1 + dy1 * dy1 + dz1 * dz1;
            float d2 = dx2 * dx2 + dy2 * dy2 + dz2 * dz2;
            float d3 = dx3 * dx3 + dy3 * dy3 + dz3 * dz3;
            ca = fminf(ca, fminf(d0, d1));
            cb = fminf(cb, fminf(d2, d3));
        }
        g_ws[GW_COL(z, pb, tid)] = fminf(ca, cb);   // BIGV if nxc==0 (gated later)
    }

    // pass-1 sum reduce (wave 0 only holds nonzero sum)
    for (int off = 32; off > 0; off >>= 1) sum += __shfl_down(sum, off);
    if (tid == 0) {
        g_ws[GW_QUAL(z, pb)] = sum;
        g_ws[GW_NX(z, pb)] = (float)nxc;
    }
}

// One block per pb=(i,b): min-combine the 8 colmin planes, gate by y-validity.
__global__ __launch_bounds__(256) void colsum_kernel(
    const float* __restrict__ opt)
{
    const int pb = blockIdx.x;
    const int tid = threadIdx.x;
    __shared__ float red[4];
    __shared__ int redc[4];

    const size_t optbase = (size_t)pb * MM;
    float sum = 0.0f;
    int cnt = 0;
#pragma unroll
    for (int s = 0; s < 2; ++s) {
        int j = s * 256 + tid;
        const float* y = opt + (optbase + j) * 3;
        bool v = (y[0] != 0.0f) | (y[1] != 0.0f) | (y[2] != 0.0f);
        float m = BIGV;
#pragma unroll
        for (int z = 0; z < XCHUNKS; ++z) m = fminf(m, g_ws[GW_COL(z, pb, j)]);
        if (v) { sum += m; cnt++; }     // nx==0 overall -> BIGV, gated in finalize
    }
    for (int off = 32; off > 0; off >>= 1) {
        sum += __shfl_down(sum, off);
        cnt += __shfl_down(cnt, off);
    }
    if ((tid & 63) == 0) { red[tid >> 6] = sum; redc[tid >> 6] = cnt; }
    __syncthreads();
    if (tid == 0) {
        g_ws[GW_COV(pb)] = red[0] + red[1] + red[2] + red[3];
        g_ws[GW_NY(pb)] = (float)(redc[0] + redc[1] + redc[2] + redc[3]);
    }
}

__global__ __launch_bounds__(256) void finalize_kernel(
    const float* __restrict__ probs,   // (P,B,1)
    const float* __restrict__ mu,      // (B,DLAT)
    const float* __restrict__ logvar,  // (B,DLAT)
    float* __restrict__ out)
{
    const int tid = threadIdx.x;
    __shared__ float red[4];
    __shared__ float s_wq[PB], s_wc[PB], s_val[PB];

    const float4* mu4 = reinterpret_cast<const float4*>(mu);
    const float4* lv4 = reinterpret_cast<const float4*>(logvar);
    float kls = 0.0f;
    for (int t = tid; t < BB * DLAT / 4; t += 256) {
        float4 m4 = mu4[t], l4 = lv4[t];
        kls += (1.0f + l4.x - m4.x * m4.x - expf(l4.x))
             + (1.0f + l4.y - m4.y * m4.y - expf(l4.y))
             + (1.0f + l4.z - m4.z * m4.z - expf(l4.z))
             + (1.0f + l4.w - m4.w * m4.w - expf(l4.w));
    }
    for (int off = 32; off > 0; off >>= 1) kls += __shfl_down(kls, off);
    if ((tid & 63) == 0) red[tid >> 6] = kls;

    if (tid < PB) {
        float qs = 0.0f, nxf = 0.0f;
#pragma unroll
        for (int z = 0; z < XCHUNKS; ++z) {
            qs += g_ws[GW_QUAL(z, tid)];
            nxf += g_ws[GW_NX(z, tid)];
        }
        float cs  = g_ws[GW_COV(tid)];
        float nyf = g_ws[GW_NY(tid)];
        bool valid = (nxf > 0.0f) && (nyf > 0.0f);
        float wgt = valid ? probs[tid] : 0.0f;
        s_wq[tid] = wgt * (qs / fmaxf(nxf, 1.0f));
        s_wc[tid] = wgt * (cs / fmaxf(nyf, 1.0f));
        s_val[tid] = valid ? 1.0f : 0.0f;
    }
    __syncthreads();

    if (tid == 0) {
        float kld = -0.5f * (red[0] + red[1] + red[2] + red[3]) / (float)BB;
        float ch = 0.0f, cov = 0.0f, qu = 0.0f, num = 0.0f;
        for (int ii = 0; ii < PP; ++ii) {
            float sq = 0.0f, sc = 0.0f, n = 0.0f;
            for (int bb = 0; bb < BB; ++bb) {
                sq += s_wq[ii * BB + bb];
                sc += s_wc[ii * BB + bb];
                n += s_val[ii * BB + bb];
            }
            float has = (n > 0.0f) ? 1.0f : 0.0f;
            float invn = has / fmaxf(n, 1.0f);
            qu += sq * invn;
            cov += sc * invn;
            ch += (sq + sc) * invn;
            num += has;
        }
        float invnum = 1.0f / fmaxf(num, 1.0f);
        float cds = ch * invnum;
        out[0] = cds + BETA_C * kld;
        out[1] = cds;
        out[2] = cov * invnum;
        out[3] = qu * invnum;
        out[4] = kld;
    }
}

extern "C" void kernel_launch(void* const* d_in, const int* in_sizes, int n_in,
                              void* d_out, int out_size, void* d_ws, size_t ws_size,
                              hipStream_t stream) {
    const float* ipt    = (const float*)d_in[0];
    const float* opt    = (const float*)d_in[1];
    const float* trans  = (const float*)d_in[2];
    const float* rots   = (const float*)d_in[3];
    const float* probs  = (const float*)d_in[4];
    const int*   idx    = (const int*)d_in[5];
    const float* mu     = (const float*)d_in[6];
    const float* logvar = (const float*)d_in[7];
    float* out = (float*)d_out;
    (void)d_ws; (void)ws_size; (void)in_sizes; (void)n_in; (void)out_size;

    dim3 grid(BB, PP, XCHUNKS);
    parts_kernel<<<grid, THREADS, 0, stream>>>(ipt, opt, trans, rots, idx);
    colsum_kernel<<<PB, 256, 0, stream>>>(opt);
    finalize_kernel<<<1, 256, 0, stream>>>(probs, mu, logvar, out);
}

// Round 13
// 91.342 us; speedup vs baseline: 1.2912x; 1.0322x over previous
//
#include <hip/hip_runtime.h>
#include <math.h>

#define PP 4
#define BB 32
#define PB (PP * BB)
#define NN 2048
#define MM 512
#define DLAT 128
#define BETA_C 1e-3f
#define BIGV 1e9f
#define SENT 1e8f
#define THREADS 512
#define NWAVE 8
#define QCHUNKS 4
#define CCHUNKS 4
#define QCH (NN / QCHUNKS)    // 512 n-range per quality chunk
#define CCH (MM / CCHUNKS)    // 128 y per coverage chunk
#define XMAX (NN + 32)

// Device-global scratch, disjoint slot per chunk-block (no atomics, no init).
// Planes of PB floats: 0..3 qual[z] | 4..7 cov[c] | 8..11 nx[z] | 12..15 ny[c]
// Every plane cell written by exactly one block each launch -> replay-safe.
__device__ float g_ws[16 * PB];

__device__ __forceinline__ int wave_compact_slot(bool sel, int* s_cnt, int lane) {
    unsigned long long bal = __ballot(sel);
    int lofs = __popcll(bal & ((1ull << lane) - 1ull));
    int base = 0;
    if (lane == 0 && bal) base = atomicAdd(s_cnt, __popcll(bal));
    base = __shfl(base, 0);
    return base + lofs;
}

// One block per (b, i, z). z<QCHUNKS: quality x-chunk; else coverage y-chunk.
// 1024 blocks x 512 thr (VGPR capped for 8 waves/SIMD) -> 4 blocks/CU ->
// 32 waves/CU full occupancy. Wave-split streaming + pmin combine. This is
// the session-best configuration (round 10: 92.2 us total, parts ~22 us).
__global__ __launch_bounds__(THREADS, 8) void parts_kernel(
    const float* __restrict__ ipt,    // (B,N,3)
    const float* __restrict__ opt,    // (P,B,M,3)
    const float* __restrict__ trans,  // (P,B,3)
    const float* __restrict__ rots,   // (P,B,4)
    const int*   __restrict__ idx)    // (B,N)
{
    const int b = blockIdx.x;
    const int i = blockIdx.y;
    const int z = blockIdx.z;
    const int tid = threadIdx.x;
    const int lane = tid & 63;
    const int w = tid >> 6;

    __shared__ float Rm[12];
    __shared__ int s_nx, s_ny;
    __shared__ __align__(16) float syx[MM], syy[MM], syz[MM];
    __shared__ __align__(16) float sxx[XMAX], sxy[XMAX], sxz[XMAX];
    __shared__ float pmin[NWAVE][128];
    __shared__ float red[NWAVE];

    if (tid == 0) {
        s_nx = 0;
        s_ny = 0;
        const float* q = rots + (i * BB + b) * 4;
        float qw = q[0], qx = q[1], qy = q[2], qz = q[3];
        float inv = 1.0f / sqrtf(qw * qw + qx * qx + qy * qy + qz * qz);
        qw *= inv; qx *= inv; qy *= inv; qz *= inv;
        Rm[0] = 1.0f - 2.0f * (qy * qy + qz * qz);
        Rm[1] = 2.0f * (qx * qy - qw * qz);
        Rm[2] = 2.0f * (qx * qz + qw * qy);
        Rm[3] = 2.0f * (qx * qy + qw * qz);
        Rm[4] = 1.0f - 2.0f * (qx * qx + qz * qz);
        Rm[5] = 2.0f * (qy * qz - qw * qx);
        Rm[6] = 2.0f * (qx * qz - qw * qy);
        Rm[7] = 2.0f * (qy * qz + qw * qx);
        Rm[8] = 1.0f - 2.0f * (qx * qx + qy * qy);
        const float* t = trans + (i * BB + b) * 3;
        Rm[9] = t[0]; Rm[10] = t[1]; Rm[11] = t[2];
    }
    __syncthreads();

    const float R0 = Rm[0], R1 = Rm[1], R2 = Rm[2];
    const float R3 = Rm[3], R4 = Rm[4], R5 = Rm[5];
    const float R6 = Rm[6], R7 = Rm[7], R8 = Rm[8];
    const float t0 = Rm[9], t1 = Rm[10], t2 = Rm[11];
    const size_t optbase = ((size_t)i * BB + b) * MM;
    const int pb = i * BB + b;

    float sum = 0.0f;

    if (z < QCHUNKS) {
        // ---------------- quality x-chunk z ----------------
        for (int m = tid; m < MM; m += THREADS) {       // stage all y, SoA
            const float* y = opt + (optbase + m) * 3;
            float yx = y[0], yy = y[1], yz = y[2];
            bool v = (yx != 0.0f) | (yy != 0.0f) | (yz != 0.0f);
            if (!v) { yx = SENT; yy = SENT; yz = SENT; }
            syx[m] = yx; syy[m] = yy; syz[m] = yz;
        }
        const int n0 = z * QCH;                         // compact this n-range
        for (int n = n0 + tid; n < n0 + QCH; n += THREADS) {
            const float* p = ipt + ((size_t)b * NN + n) * 3;
            float px = p[0], py = p[1], pz = p[2];
            bool nz = (px != 0.0f) | (py != 0.0f) | (pz != 0.0f);
            bool sel = nz && (idx[b * NN + n] == i);
            int pos = wave_compact_slot(sel, &s_nx, lane);
            if (sel) {
                px -= t0; py -= t1; pz -= t2;
                sxx[pos] = R0 * px + R1 * py + R2 * pz;
                sxy[pos] = R3 * px + R4 * py + R5 * pz;
                sxz[pos] = R6 * px + R7 * py + R8 * pz;
            }
        }
        __syncthreads();
        const int nxc = s_nx;
        const int y0 = w * (MM / NWAVE);                // wave's 64-y stream

        for (int base = 0; base < nxc; base += 128) {   // typically one pass
            float px[2], py[2], pz[2], mn[2];
#pragma unroll
            for (int s = 0; s < 2; ++s) {
                int k = base + s * 64 + lane;
                bool a = (k < nxc);
                px[s] = a ? sxx[k] : SENT;
                py[s] = a ? sxy[k] : SENT;
                pz[s] = a ? sxz[k] : SENT;
                mn[s] = BIGV;
            }
            for (int j = 0; j < MM / NWAVE; j += 4) {   // wave-uniform broadcast b128
                float4 yx = *reinterpret_cast<const float4*>(syx + y0 + j);
                float4 yy = *reinterpret_cast<const float4*>(syy + y0 + j);
                float4 yz = *reinterpret_cast<const float4*>(syz + y0 + j);
#pragma unroll
                for (int s = 0; s < 2; ++s) {
                    float dx0 = px[s] - yx.x, dy0 = py[s] - yy.x, dz0 = pz[s] - yz.x;
                    float dx1 = px[s] - yx.y, dy1 = py[s] - yy.y, dz1 = pz[s] - yz.y;
                    float dx2 = px[s] - yx.z, dy2 = py[s] - yy.z, dz2 = pz[s] - yz.z;
                    float dx3 = px[s] - yx.w, dy3 = py[s] - yy.w, dz3 = pz[s] - yz.w;
                    float d0 = dx0 * dx0 + dy0 * dy0 + dz0 * dz0;
                    float d1 = dx1 * dx1 + dy1 * dy1 + dz1 * dz1;
                    float d2 = dx2 * dx2 + dy2 * dy2 + dz2 * dz2;
                    float d3 = dx3 * dx3 + dy3 * dy3 + dz3 * dz3;
                    mn[s] = fminf(mn[s], fminf(fminf(d0, d1), fminf(d2, d3)));
                }
            }
#pragma unroll
            for (int s = 0; s < 2; ++s) pmin[w][s * 64 + lane] = mn[s];
            __syncthreads();
            if (tid < 128 && base + tid < nxc) {
                float m = pmin[0][tid];
#pragma unroll
                for (int ww = 1; ww < NWAVE; ++ww) m = fminf(m, pmin[ww][tid]);
                sum += m;
            }
            __syncthreads();
        }

        for (int off = 32; off > 0; off >>= 1) sum += __shfl_down(sum, off);
        if (lane == 0) red[w] = sum;
        __syncthreads();
        if (tid == 0) {
            float tot = 0.0f;
            for (int ww = 0; ww < NWAVE; ++ww) tot += red[ww];
            g_ws[(0 + z) * PB + pb] = tot;              // qual partial
            g_ws[(8 + z) * PB + pb] = (float)s_nx;      // nx partial
        }
    } else {
        // ---------------- coverage y-chunk c ----------------
        const int c = z - QCHUNKS;
        if (tid < CCH) {                                // stage 128 y (waves 0-1, full)
            const float* y = opt + (optbase + c * CCH + tid) * 3;
            float yx = y[0], yy = y[1], yz = y[2];
            bool v = (yx != 0.0f) | (yy != 0.0f) | (yz != 0.0f);
            if (!v) { yx = SENT; yy = SENT; yz = SENT; }
            syx[tid] = yx; syy[tid] = yy; syz[tid] = yz;
            unsigned long long bal = __ballot(v);
            if (lane == 0) atomicAdd(&s_ny, __popcll(bal));
        }
        for (int n = tid; n < NN; n += THREADS) {       // compact FULL x of part i
            const float* p = ipt + ((size_t)b * NN + n) * 3;
            float px = p[0], py = p[1], pz = p[2];
            bool nz = (px != 0.0f) | (py != 0.0f) | (pz != 0.0f);
            bool sel = nz && (idx[b * NN + n] == i);
            int pos = wave_compact_slot(sel, &s_nx, lane);
            if (sel) {
                px -= t0; py -= t1; pz -= t2;
                sxx[pos] = R0 * px + R1 * py + R2 * pz;
                sxy[pos] = R3 * px + R4 * py + R5 * pz;
                sxz[pos] = R6 * px + R7 * py + R8 * pz;
            }
        }
        __syncthreads();
        const int nx = s_nx;
        const int ny = s_ny;
        const int nx32 = (nx + 31) & ~31;               // 8 wave-slices, each %4==0
        if (tid < nx32 - nx) {
            sxx[nx + tid] = SENT; sxy[nx + tid] = SENT; sxz[nx + tid] = SENT;
        }
        __syncthreads();

        float qx[2], qy[2], qz[2], mn[2];
#pragma unroll
        for (int s = 0; s < 2; ++s) {                   // lane's 2 y slots
            int j = s * 64 + lane;
            qx[s] = syx[j]; qy[s] = syy[j]; qz[s] = syz[j];
            mn[s] = BIGV;
        }
        const int q = nx32 / NWAVE;
        const int x0 = w * q;
        for (int k = 0; k < q; k += 4) {                // wave-uniform broadcast b128
            float4 xx = *reinterpret_cast<const float4*>(sxx + x0 + k);
            float4 xy = *reinterpret_cast<const float4*>(sxy + x0 + k);
            float4 xz = *reinterpret_cast<const float4*>(sxz + x0 + k);
#pragma unroll
            for (int s = 0; s < 2; ++s) {
                float dx0 = qx[s] - xx.x, dy0 = qy[s] - xy.x, dz0 = qz[s] - xz.x;
                float dx1 = qx[s] - xx.y, dy1 = qy[s] - xy.y, dz1 = qz[s] - xz.y;
                float dx2 = qx[s] - xx.z, dy2 = qy[s] - xy.z, dz2 = qz[s] - xz.z;
                float dx3 = qx[s] - xx.w, dy3 = qy[s] - xy.w, dz3 = qz[s] - xz.w;
                float d0 = dx0 * dx0 + dy0 * dy0 + dz0 * dz0;
                float d1 = dx1 * dx1 + dy1 * dy1 + dz1 * dz1;
                float d2 = dx2 * dx2 + dy2 * dy2 + dz2 * dz2;
                float d3 = dx3 * dx3 + dy3 * dy3 + dz3 * dz3;
                mn[s] = fminf(mn[s], fminf(fminf(d0, d1), fminf(d2, d3)));
            }
        }
#pragma unroll
        for (int s = 0; s < 2; ++s) pmin[w][s * 64 + lane] = mn[s];   // BIGV if q==0
        __syncthreads();
        if (tid < CCH && syx[tid] != SENT) {            // valid y only
            float m = pmin[0][tid];
#pragma unroll
            for (int ww = 1; ww < NWAVE; ++ww) m = fminf(m, pmin[ww][tid]);
            sum += m;                                   // nx==0 -> BIGV, gated in finalize
        }
        __syncthreads();

        for (int off = 32; off > 0; off >>= 1) sum += __shfl_down(sum, off);
        if (lane == 0) red[w] = sum;
        __syncthreads();
        if (tid == 0) {
            float tot = 0.0f;
            for (int ww = 0; ww < NWAVE; ++ww) tot += red[ww];
            g_ws[(4 + c) * PB + pb] = tot;              // cov partial
            g_ws[(12 + c) * PB + pb] = (float)ny;       // ny partial
        }
    }
}

__global__ __launch_bounds__(256) void finalize_kernel(
    const float* __restrict__ probs,   // (P,B,1)
    const float* __restrict__ mu,      // (B,DLAT)
    const float* __restrict__ logvar,  // (B,DLAT)
    float* __restrict__ out)
{
    const int tid = threadIdx.x;
    __shared__ float red[4];
    __shared__ float s_wq[PB], s_wc[PB], s_val[PB];

    // KL over B*DLAT, float4-vectorized
    const float4* mu4 = reinterpret_cast<const float4*>(mu);
    const float4* lv4 = reinterpret_cast<const float4*>(logvar);
    float kls = 0.0f;
    for (int t = tid; t < BB * DLAT / 4; t += 256) {
        float4 m4 = mu4[t], l4 = lv4[t];
        kls += (1.0f + l4.x - m4.x * m4.x - expf(l4.x))
             + (1.0f + l4.y - m4.y * m4.y - expf(l4.y))
             + (1.0f + l4.z - m4.z * m4.z - expf(l4.z))
             + (1.0f + l4.w - m4.w * m4.w - expf(l4.w));
    }
    for (int off = 32; off > 0; off >>= 1) kls += __shfl_down(kls, off);
    if ((tid & 63) == 0) red[tid >> 6] = kls;

    if (tid < PB) {
        float qs  = g_ws[0 * PB + tid] + g_ws[1 * PB + tid] + g_ws[2 * PB + tid] + g_ws[3 * PB + tid];
        float cs  = g_ws[4 * PB + tid] + g_ws[5 * PB + tid] + g_ws[6 * PB + tid] + g_ws[7 * PB + tid];
        float nxf = g_ws[8 * PB + tid] + g_ws[9 * PB + tid] + g_ws[10 * PB + tid] + g_ws[11 * PB + tid];
        float nyf = g_ws[12 * PB + tid] + g_ws[13 * PB + tid] + g_ws[14 * PB + tid] + g_ws[15 * PB + tid];
        bool valid = (nxf > 0.0f) && (nyf > 0.0f);
        float wgt = valid ? probs[tid] : 0.0f;
        s_wq[tid] = wgt * (qs / fmaxf(nxf, 1.0f));
        s_wc[tid] = wgt * (cs / fmaxf(nyf, 1.0f));
        s_val[tid] = valid ? 1.0f : 0.0f;
    }
    __syncthreads();

    if (tid == 0) {
        float kld = -0.5f * (red[0] + red[1] + red[2] + red[3]) / (float)BB;
        float ch = 0.0f, cov = 0.0f, qu = 0.0f, num = 0.0f;
        for (int ii = 0; ii < PP; ++ii) {
            float sq = 0.0f, sc = 0.0f, n = 0.0f;
            for (int bb = 0; bb < BB; ++bb) {
                sq += s_wq[ii * BB + bb];
                sc += s_wc[ii * BB + bb];
                n += s_val[ii * BB + bb];
            }
            float has = (n > 0.0f) ? 1.0f : 0.0f;
            float invn = has / fmaxf(n, 1.0f);
            qu += sq * invn;
            cov += sc * invn;
            ch += (sq + sc) * invn;
            num += has;
        }
        float invnum = 1.0f / fmaxf(num, 1.0f);
        float cds = ch * invnum;
        out[0] = cds + BETA_C * kld;
        out[1] = cds;
        out[2] = cov * invnum;
        out[3] = qu * invnum;
        out[4] = kld;
    }
}

extern "C" void kernel_launch(void* const* d_in, const int* in_sizes, int n_in,
                              void* d_out, int out_size, void* d_ws, size_t ws_size,
                              hipStream_t stream) {
    const float* ipt    = (const float*)d_in[0];
    const float* opt    = (const float*)d_in[1];
    const float* trans  = (const float*)d_in[2];
    const float* rots   = (const float*)d_in[3];
    const float* probs  = (const float*)d_in[4];
    const int*   idx    = (const int*)d_in[5];
    const float* mu     = (const float*)d_in[6];
    const float* logvar = (const float*)d_in[7];
    float* out = (float*)d_out;
    (void)d_ws; (void)ws_size; (void)in_sizes; (void)n_in; (void)out_size;

    dim3 grid(BB, PP, QCHUNKS + CCHUNKS);
    parts_kernel<<<grid, THREADS, 0, stream>>>(ipt, opt, trans, rots, idx);
    finalize_kernel<<<1, 256, 0, stream>>>(probs, mu, logvar, out);
}